// Round 1
// baseline (744.115 us; speedup 1.0000x reference)
//
#include <hip/hip_runtime.h>
#include <hip/hip_bf16.h>
#include <cstdint>

typedef __attribute__((ext_vector_type(8))) short s16x8;   // 8 bf16 (4 VGPRs)
typedef __attribute__((ext_vector_type(4))) float f32x4;   // MFMA accumulator

#define DEVI static __device__ __forceinline__

constexpr int NB = 4, LQ = 2048, DM = 1024, NH = 16, HD = 64;

DEVI ushort f2b(float f) {
    __hip_bfloat16 h = __float2bfloat16(f);
    return __builtin_bit_cast(ushort, h);
}

DEVI void gl16(const void* gsrc, void* ldst) {
    __builtin_amdgcn_global_load_lds(
        (const __attribute__((address_space(1))) void*)gsrc,
        (__attribute__((address_space(3))) void*)ldst, 16, 0, 0);
}

// ---------------- fp32 -> bf16 cast, vectorized ----------------
__global__ __launch_bounds__(256) void cvt_f32_bf16(const float* __restrict__ in,
                                                    ushort* __restrict__ out, int n4) {
    int i = blockIdx.x * 256 + threadIdx.x;
    if (i < n4) {
        float4 v = reinterpret_cast<const float4*>(in)[i];
        ushort4 o;
        o.x = f2b(v.x); o.y = f2b(v.y); o.z = f2b(v.z); o.w = f2b(v.w);
        reinterpret_cast<ushort4*>(out)[i] = o;
    }
}

// ---------------- mask bit-pack: int32 0/1 -> bitmask ----------------
__global__ __launch_bounds__(256) void pack_mask(const int* __restrict__ M,
                                                 unsigned int* __restrict__ Mp) {
    size_t i = (size_t)blockIdx.x * 256 + threadIdx.x;
    unsigned long long b = __ballot(M[i] != 0);
    int lane = threadIdx.x & 63;
    if (lane == 0)       Mp[i >> 5] = (unsigned int)b;
    else if (lane == 32) Mp[i >> 5] = (unsigned int)(b >> 32);
}

// ---------------- bf16 GEMM: C[8192,1024] = A[8192,1024] * W[1024,1024]^T ----------------
// m97-style: 128x128 tile, BK=32, 4 waves (2x2), 4x4 16x16x32 frags per wave.
// MODE 0: out = bf16 to (N,H,L,HD) layout, value = (acc+bias)*scale
// MODE 1: out = fp32 row-major [row*1024+col], value = acc+bias
template <int MODE>
__global__ __launch_bounds__(256) void gemm_bt(const ushort* __restrict__ A,
                                               const ushort* __restrict__ W,
                                               const float* __restrict__ bias,
                                               ushort* __restrict__ outb,
                                               float* __restrict__ outf,
                                               float scale) {
    constexpr int K = 1024;
    __shared__ ushort lA[128 * 32];
    __shared__ ushort lB[128 * 32];
    const int tid = threadIdx.x;
    const int lane = tid & 63;
    const int bm = blockIdx.x, bn = blockIdx.y;
    const int wr = (tid >> 6) >> 1, wc = (tid >> 6) & 1;
    const int lr = lane & 15, lg = lane >> 4;

    f32x4 acc[4][4] = {};

    const int ch0 = tid, ch1 = tid + 256;
    const size_t a0 = (size_t)(bm * 128 + (ch0 >> 2)) * K + (ch0 & 3) * 8;
    const size_t a1 = (size_t)(bm * 128 + (ch1 >> 2)) * K + (ch1 & 3) * 8;
    const size_t b0 = (size_t)(bn * 128 + (ch0 >> 2)) * K + (ch0 & 3) * 8;
    const size_t b1 = (size_t)(bn * 128 + (ch1 >> 2)) * K + (ch1 & 3) * 8;

    for (int bk = 0; bk < K; bk += 32) {
        gl16(A + a0 + bk, (char*)lA + ch0 * 16);
        gl16(A + a1 + bk, (char*)lA + ch1 * 16);
        gl16(W + b0 + bk, (char*)lB + ch0 * 16);
        gl16(W + b1 + bk, (char*)lB + ch1 * 16);
        __syncthreads();

        s16x8 af[4], bf[4];
#pragma unroll
        for (int mi = 0; mi < 4; mi++)
            af[mi] = *(const s16x8*)&lA[(wr * 64 + mi * 16 + lr) * 32 + lg * 8];
#pragma unroll
        for (int ni = 0; ni < 4; ni++)
            bf[ni] = *(const s16x8*)&lB[(wc * 64 + ni * 16 + lr) * 32 + lg * 8];
#pragma unroll
        for (int mi = 0; mi < 4; mi++)
#pragma unroll
            for (int ni = 0; ni < 4; ni++)
                acc[mi][ni] = __builtin_amdgcn_mfma_f32_16x16x32_bf16(af[mi], bf[ni],
                                                                      acc[mi][ni], 0, 0, 0);
        __syncthreads();
    }

#pragma unroll
    for (int ni = 0; ni < 4; ni++) {
        const int col = bn * 128 + wc * 64 + ni * 16 + lr;
        const float bv = bias[col];
#pragma unroll
        for (int mi = 0; mi < 4; mi++) {
            const int row0 = bm * 128 + wr * 64 + mi * 16 + (lg << 2);
#pragma unroll
            for (int r = 0; r < 4; r++) {
                const int row = row0 + r;
                float v = acc[mi][ni][r] + bv;
                if constexpr (MODE == 0) {
                    const int n = row >> 11, l = row & 2047;
                    const int h = col >> 6, hd = col & 63;
                    outb[((((size_t)n * NH + h) * LQ + l) << 6) + hd] = f2b(v * scale);
                } else {
                    outf[(size_t)row * DM + col] = v;
                }
            }
        }
    }
}

// ---------------- flash attention ----------------
// grid (L/64, N*H), 256 thr = 4 waves, 16 q-rows per wave, KV tile = 32.
// Q,K,V bf16 in (N,H,L,64); Mp packed bits (N,L,L/32); out attn bf16 (N,L,D).
__global__ __launch_bounds__(256) void flash_attn(const ushort* __restrict__ Qb,
                                                  const ushort* __restrict__ Kb,
                                                  const ushort* __restrict__ Vb,
                                                  const unsigned int* __restrict__ Mp,
                                                  ushort* __restrict__ attnb) {
    __shared__ ushort pl[4][16 * 40];  // per-wave 16x32 P tile, padded stride 40
    const int lane = threadIdx.x & 63, wave = threadIdx.x >> 6;
    const int lr = lane & 15, lg = lane >> 4;
    const int qblk = blockIdx.x, nh = blockIdx.y;
    const int n = nh >> 4, h = nh & 15;
    const int qbase = qblk * 64 + wave * 16;

    const ushort* Qh = Qb + (size_t)nh * LQ * HD;
    const ushort* Kh = Kb + (size_t)nh * LQ * HD;
    const ushort* Vh = Vb + (size_t)nh * LQ * HD;
    const unsigned int* Mrow = Mp + (size_t)n * LQ * (LQ / 32);

    s16x8 qf[2];
#pragma unroll
    for (int ks = 0; ks < 2; ks++)
        qf[ks] = *(const s16x8*)&Qh[(size_t)(qbase + lr) * HD + ks * 32 + lg * 8];

    float m[4], lsum[4];
    f32x4 o[4] = {};
#pragma unroll
    for (int r = 0; r < 4; r++) { m[r] = -1e30f; lsum[r] = 0.f; }

    for (int kb = 0; kb < LQ; kb += 32) {
        unsigned int mw[4];
#pragma unroll
        for (int r = 0; r < 4; r++)
            mw[r] = Mrow[(size_t)(qbase + lg * 4 + r) * (LQ / 32) + (kb >> 5)];

        f32x4 s[2] = {};
#pragma unroll
        for (int ct = 0; ct < 2; ct++)
#pragma unroll
            for (int ks = 0; ks < 2; ks++) {
                s16x8 kf = *(const s16x8*)&Kh[(size_t)(kb + ct * 16 + lr) * HD + ks * 32 + lg * 8];
                s[ct] = __builtin_amdgcn_mfma_f32_16x16x32_bf16(qf[ks], kf, s[ct], 0, 0, 0);
            }

        float p[2][4], corr[4];
#pragma unroll
        for (int r = 0; r < 4; r++) {
            float s0 = ((mw[r] >> lr) & 1u)        ? s[0][r] : -1e9f;
            float s1 = ((mw[r] >> (16 + lr)) & 1u) ? s[1][r] : -1e9f;
            float mx = fmaxf(s0, s1);
            mx = fmaxf(mx, __shfl_xor(mx, 1));
            mx = fmaxf(mx, __shfl_xor(mx, 2));
            mx = fmaxf(mx, __shfl_xor(mx, 4));
            mx = fmaxf(mx, __shfl_xor(mx, 8));
            const float mnew = fmaxf(m[r], mx);
            corr[r] = __expf(m[r] - mnew);
            m[r] = mnew;
            const float e0 = __expf(s0 - mnew);   // masked: exp(-1e9-m) -> 0
            const float e1 = __expf(s1 - mnew);
            p[0][r] = e0; p[1][r] = e1;
            float ps = e0 + e1;
            ps += __shfl_xor(ps, 1);
            ps += __shfl_xor(ps, 2);
            ps += __shfl_xor(ps, 4);
            ps += __shfl_xor(ps, 8);
            lsum[r] = lsum[r] * corr[r] + ps;
        }

        // P (C-layout) -> LDS -> A-frag layout
#pragma unroll
        for (int ct = 0; ct < 2; ct++)
#pragma unroll
            for (int r = 0; r < 4; r++)
                pl[wave][(lg * 4 + r) * 40 + ct * 16 + lr] = f2b(p[ct][r]);

#pragma unroll
        for (int nt = 0; nt < 4; nt++)
#pragma unroll
            for (int r = 0; r < 4; r++) o[nt][r] *= corr[r];

        s16x8 pa = *(const s16x8*)&pl[wave][lr * 40 + lg * 8];

#pragma unroll
        for (int nt = 0; nt < 4; nt++) {
            s16x8 vf;
#pragma unroll
            for (int j = 0; j < 8; j++)
                vf[j] = (short)Vh[(size_t)(kb + lg * 8 + j) * HD + nt * 16 + lr];
            o[nt] = __builtin_amdgcn_mfma_f32_16x16x32_bf16(pa, vf, o[nt], 0, 0, 0);
        }
    }

#pragma unroll
    for (int nt = 0; nt < 4; nt++)
#pragma unroll
        for (int r = 0; r < 4; r++) {
            const int q = qbase + lg * 4 + r;
            const float v = o[nt][r] / lsum[r];
            attnb[((size_t)n * LQ + q) * DM + h * HD + nt * 16 + lr] = f2b(v);
        }
}

// ---------------- launcher ----------------
extern "C" void kernel_launch(void* const* d_in, const int* in_sizes, int n_in,
                              void* d_out, int out_size, void* d_ws, size_t ws_size,
                              hipStream_t stream) {
    const float* Hq = (const float*)d_in[0];
    const float* Hk = (const float*)d_in[1];
    const float* Hv = (const float*)d_in[2];
    const int*   Mm = (const int*)d_in[3];
    const float* Wq = (const float*)d_in[4];
    const float* bq = (const float*)d_in[5];
    const float* Wk = (const float*)d_in[6];
    const float* bk = (const float*)d_in[7];
    const float* Wv = (const float*)d_in[8];
    const float* bv = (const float*)d_in[9];
    const float* Wo = (const float*)d_in[10];
    const float* bo = (const float*)d_in[11];

    char* p = (char*)d_ws;
    ushort* Ab = (ushort*)p;      p += (size_t)8192 * 1024 * 2;  // A staging; reused as attn buffer
    ushort* Wb = (ushort*)p;      p += (size_t)1024 * 1024 * 2;
    ushort* Qb = (ushort*)p;      p += (size_t)8192 * 1024 * 2;
    ushort* Kb = (ushort*)p;      p += (size_t)8192 * 1024 * 2;
    ushort* Vb = (ushort*)p;      p += (size_t)8192 * 1024 * 2;
    unsigned int* Mp = (unsigned int*)p;  // 4*2048*64 words = 2 MB
    ushort* attnb = Ab;

    dim3 gg(64, 8), bb(256);

    // Q projection ((acc+b)*0.125 folds the 1/sqrt(HD) into Q)
    cvt_f32_bf16<<<8192, 256, 0, stream>>>(Hq, Ab, 8192 * 1024 / 4);
    cvt_f32_bf16<<<1024, 256, 0, stream>>>(Wq, Wb, 1024 * 1024 / 4);
    gemm_bt<0><<<gg, bb, 0, stream>>>(Ab, Wb, bq, Qb, nullptr, 0.125f);
    // K projection
    cvt_f32_bf16<<<8192, 256, 0, stream>>>(Hk, Ab, 8192 * 1024 / 4);
    cvt_f32_bf16<<<1024, 256, 0, stream>>>(Wk, Wb, 1024 * 1024 / 4);
    gemm_bt<0><<<gg, bb, 0, stream>>>(Ab, Wb, bk, Kb, nullptr, 1.0f);
    // V projection
    cvt_f32_bf16<<<8192, 256, 0, stream>>>(Hv, Ab, 8192 * 1024 / 4);
    cvt_f32_bf16<<<1024, 256, 0, stream>>>(Wv, Wb, 1024 * 1024 / 4);
    gemm_bt<0><<<gg, bb, 0, stream>>>(Ab, Wb, bv, Vb, nullptr, 1.0f);
    // mask pack
    pack_mask<<<65536, 256, 0, stream>>>(Mm, Mp);
    // attention (writes attnb = Ab region, dead after V projection)
    flash_attn<<<dim3(32, 64), 256, 0, stream>>>(Qb, Kb, Vb, Mp, attnb);
    // output projection
    cvt_f32_bf16<<<1024, 256, 0, stream>>>(Wo, Wb, 1024 * 1024 / 4);
    gemm_bt<1><<<gg, bb, 0, stream>>>(attnb, Wb, bo, nullptr, (float*)d_out, 1.0f);
}